// Round 5
// baseline (304.727 us; speedup 1.0000x reference)
//
#include <hip/hip_runtime.h>

// SSIM loss, fused, vertical-first. fp32 [16,3,512,512] x2 -> scalar.
// Per block: 56x16 output tile, 256 threads = 16 rows x 16 col-groups of 4.
// Pass 1 (registers, no LDS): vertical 7-tap over 5 channels (x,y,xx,yy,xy)
//   straight from global via guarded float4 loads (L1/L2 absorb 7x row reuse).
// LDS round-trip: 5 float4 writes/thread, barrier, 15 aligned b128 reads/thread.
// Pass 2: horizontal 7-tap (static indices) + SSIM map + shuffle reduce +
// one atomicAdd per block: out = sum_b (1/NBLK - s_b/N).

#define IMG 512
#define TW 56
#define TH 16
#define NGX 10                               // ceil(512/56)
#define NPLANES 48
#define NBLK (NGX * (IMG / TH) * NPLANES)    // 10*32*48 = 15360
#define SSIM_C1 1.0e-4f
#define SSIM_C2 9.0e-4f

__global__ __launch_bounds__(256) void ssim_main(
    const float* __restrict__ X, const float* __restrict__ Y,
    float* __restrict__ out) {
  __shared__ float hs[5][TH][64];            // input cols [x0-4, x0+60)

  const int tid = threadIdx.x;
  const int r = tid >> 4;                    // output row in tile 0..15
  const int g = tid & 15;                    // col group 0..15
  const int x0 = blockIdx.x * TW;
  const int gy = blockIdx.y * TH + r;        // output row, always < 512
  const int plane = blockIdx.z;
  const float* __restrict__ xp = X + (size_t)plane * IMG * IMG;
  const float* __restrict__ yp = Y + (size_t)plane * IMG * IMG;

  const float gw[7] = {0.03663284536f, 0.11128076166f, 0.21674531251f,
                       0.27068216094f, 0.21674531251f, 0.11128076166f,
                       0.03663284536f};

  // ---- Pass 1: vertical 7-tap, 4 cols per thread, straight from global ----
  const int gx = x0 - 4 + 4 * g;             // float4 base col (multiple of 4)
  const bool colok = ((unsigned)gx < (unsigned)IMG);  // gx in [0,508] => fully valid

  float v1[4] = {0.f, 0.f, 0.f, 0.f}, v2[4] = {0.f, 0.f, 0.f, 0.f};
  float vxx[4] = {0.f, 0.f, 0.f, 0.f}, vyy[4] = {0.f, 0.f, 0.f, 0.f};
  float vxy[4] = {0.f, 0.f, 0.f, 0.f};

#pragma unroll
  for (int d = 0; d < 7; ++d) {
    const int ry = gy + d - 3;
    const bool ok = colok && ((unsigned)ry < (unsigned)IMG);
    const float4 z4 = make_float4(0.f, 0.f, 0.f, 0.f);
    const size_t off = (size_t)ry * IMG + gx;
    const float4 xv = ok ? *(const float4*)(xp + off) : z4;
    const float4 yv = ok ? *(const float4*)(yp + off) : z4;
    const float gk = gw[d];
    const float xa[4] = {xv.x, xv.y, xv.z, xv.w};
    const float ya[4] = {yv.x, yv.y, yv.z, yv.w};
#pragma unroll
    for (int p = 0; p < 4; ++p) {
      const float t1 = gk * xa[p];
      const float t2 = gk * ya[p];
      v1[p] += t1;
      v2[p] += t2;
      vxx[p] = __builtin_fmaf(t1, xa[p], vxx[p]);
      vyy[p] = __builtin_fmaf(t2, ya[p], vyy[p]);
      vxy[p] = __builtin_fmaf(t1, ya[p], vxy[p]);
    }
  }

  const int lb = 4 * g;
  *(float4*)&hs[0][r][lb] = make_float4(v1[0], v1[1], v1[2], v1[3]);
  *(float4*)&hs[1][r][lb] = make_float4(v2[0], v2[1], v2[2], v2[3]);
  *(float4*)&hs[2][r][lb] = make_float4(vxx[0], vxx[1], vxx[2], vxx[3]);
  *(float4*)&hs[3][r][lb] = make_float4(vyy[0], vyy[1], vyy[2], vyy[3]);
  *(float4*)&hs[4][r][lb] = make_float4(vxy[0], vxy[1], vxy[2], vxy[3]);
  __syncthreads();

  // ---- Pass 2: horizontal 7-tap + SSIM, groups 0..13 active (56 cols) ----
  float ssim_acc = 0.f;
  if (g < 14) {
    float w1[12], w2[12], w3[12], w4[12], w5[12];
#define LOADW(W, CH)                                                     \
  {                                                                      \
    const float4 a = *(const float4*)&hs[CH][r][lb];                     \
    const float4 b = *(const float4*)&hs[CH][r][lb + 4];                 \
    const float4 c = *(const float4*)&hs[CH][r][lb + 8];                 \
    W[0] = a.x; W[1] = a.y; W[2] = a.z; W[3] = a.w;                      \
    W[4] = b.x; W[5] = b.y; W[6] = b.z; W[7] = b.w;                      \
    W[8] = c.x; W[9] = c.y; W[10] = c.z; W[11] = c.w;                    \
  }
    LOADW(w1, 0)
    LOADW(w2, 1)
    LOADW(w3, 2)
    LOADW(w4, 3)
    LOADW(w5, 4)
#undef LOADW

#pragma unroll
    for (int p = 0; p < 4; ++p) {
      float mu1 = 0.f, mu2 = 0.f, exx = 0.f, eyy = 0.f, exy = 0.f;
#pragma unroll
      for (int k = 0; k < 7; ++k) {
        const float gk = gw[k];
        const int j = 1 + p + k;
        mu1 = __builtin_fmaf(gk, w1[j], mu1);
        mu2 = __builtin_fmaf(gk, w2[j], mu2);
        exx = __builtin_fmaf(gk, w3[j], exx);
        eyy = __builtin_fmaf(gk, w4[j], eyy);
        exy = __builtin_fmaf(gk, w5[j], exy);
      }
      const float mu1sq = mu1 * mu1;
      const float mu2sq = mu2 * mu2;
      const float mu12 = mu1 * mu2;
      const float sig1 = exx - mu1sq;
      const float sig2 = eyy - mu2sq;
      const float sig12 = exy - mu12;
      const float num = (2.f * mu12 + SSIM_C1) * (2.f * sig12 + SSIM_C2);
      const float den =
          (mu1sq + mu2sq + SSIM_C1) * (sig1 + sig2 + SSIM_C2);
      const int gc = x0 + 4 * g + p;
      ssim_acc += (gc < IMG) ? num * __builtin_amdgcn_rcpf(den) : 0.f;
    }
  }

  // ---- Block reduction (4 waves) + atomic fold-in ----
#pragma unroll
  for (int off = 32; off > 0; off >>= 1)
    ssim_acc += __shfl_down(ssim_acc, off, 64);
  __shared__ float wsum[4];
  if ((tid & 63) == 0) wsum[tid >> 6] = ssim_acc;
  __syncthreads();
  if (tid == 0) {
    const float s = wsum[0] + wsum[1] + wsum[2] + wsum[3];
    const float inv_n = 1.0f / (48.0f * 512.0f * 512.0f);
    atomicAdd(out, 1.0f / (float)NBLK - s * inv_n);
  }
}

extern "C" void kernel_launch(void* const* d_in, const int* in_sizes, int n_in,
                              void* d_out, int out_size, void* d_ws, size_t ws_size,
                              hipStream_t stream) {
  const float* enhanced = (const float*)d_in[0];
  const float* target = (const float*)d_in[1];
  float* out = (float*)d_out;

  hipMemsetAsync(out, 0, sizeof(float), stream);
  dim3 grid(NGX, IMG / TH, NPLANES);   // 10 x 32 x 48 = 15360
  ssim_main<<<grid, dim3(256), 0, stream>>>(enhanced, target, out);
}

// Round 6
// 262.064 us; speedup vs baseline: 1.1628x; 1.1628x over previous
//
#include <hip/hip_runtime.h>

// SSIM loss, fused, 3-phase LDS, fully vectorized. fp32 [16,3,512,512] x2 -> scalar.
// Per 256-thread block: 64x16 output tile.
//  Phase S: stage x,y rows [row0, row0+22) x cols [x0-4, x0+68) into LDS via
//           all-or-nothing float4 global loads + ds_write_b128.
//  Phase H: horizontal 7-tap, 4 px/item, 3 b128 reads per array (12-float
//           window, static extraction), 5 channels -> LDS (stride 64, b128).
//  Phase V: vertical 7-tap, 4 CONSECUTIVE rows x 1 col per thread -> 50
//           conflict-free ds_read_b32 (tap sharing), SSIM, reduce, atomicAdd.

#define IMG 512
#define TW 64
#define TH 16
#define HR 22                  // TH + 6
#define SW 72                  // staged cols [x0-4, x0+68), mult of 4
#define NSTG (HR * (SW / 4))   // 396 float4 items per array
#define NBLK ((IMG / TW) * (IMG / TH) * 48)  // 12288
#define SSIM_C1 1.0e-4f
#define SSIM_C2 9.0e-4f

__global__ __launch_bounds__(256) void ssim_main(
    const float* __restrict__ X, const float* __restrict__ Y,
    float* __restrict__ out) {
  // Layout: [stage_x: 22*72][stage_y: 22*72][ho: 5*22*64]
  __shared__ float smem[2 * HR * SW + 5 * HR * 64];
  float* const sX = smem;
  float* const sY = smem + HR * SW;
  float* const ho = smem + 2 * HR * SW;

  const int tid = threadIdx.x;
  const int x0 = blockIdx.x * TW;
  const int row0 = blockIdx.y * TH - 3;
  const float* __restrict__ xp = X + (size_t)blockIdx.z * IMG * IMG;
  const float* __restrict__ yp = Y + (size_t)blockIdx.z * IMG * IMG;

  const float gw[7] = {0.03663284536f, 0.11128076166f, 0.21674531251f,
                       0.27068216094f, 0.21674531251f, 0.11128076166f,
                       0.03663284536f};

  // ---- Phase S: stage both arrays (float4 granularity, zero-filled OOB) ----
#pragma unroll 2
  for (int i = tid; i < NSTG; i += 256) {
    const int r = i / (SW / 4);
    const int c4 = (i - r * (SW / 4)) * 4;       // staged col offset, mult of 4
    const int gy = row0 + r;
    const int gx = x0 - 4 + c4;
    const bool ok = ((unsigned)gy < (unsigned)IMG) && ((unsigned)gx <= 508u);
    const float4 z4 = make_float4(0.f, 0.f, 0.f, 0.f);
    const size_t off = (size_t)gy * IMG + gx;
    const float4 v = ok ? *(const float4*)(xp + off) : z4;
    *(float4*)&sX[r * SW + c4] = v;
  }
#pragma unroll 2
  for (int i = tid; i < NSTG; i += 256) {
    const int r = i / (SW / 4);
    const int c4 = (i - r * (SW / 4)) * 4;
    const int gy = row0 + r;
    const int gx = x0 - 4 + c4;
    const bool ok = ((unsigned)gy < (unsigned)IMG) && ((unsigned)gx <= 508u);
    const float4 z4 = make_float4(0.f, 0.f, 0.f, 0.f);
    const size_t off = (size_t)gy * IMG + gx;
    const float4 v = ok ? *(const float4*)(yp + off) : z4;
    *(float4*)&sY[r * SW + c4] = v;
  }
  __syncthreads();

  // ---- Phase H: horizontal 7-tap, 4 px per item, 22*16 = 352 items ----
#pragma unroll 2
  for (int i = tid; i < HR * 16; i += 256) {
    const int r = i >> 4, g = i & 15;
    const int base = r * SW + 4 * g;             // window cols [4g, 4g+12)
    const float4 a0 = *(const float4*)&sX[base];
    const float4 a1 = *(const float4*)&sX[base + 4];
    const float4 a2 = *(const float4*)&sX[base + 8];
    const float4 b0 = *(const float4*)&sY[base];
    const float4 b1 = *(const float4*)&sY[base + 4];
    const float4 b2 = *(const float4*)&sY[base + 8];
    const float wx[12] = {a0.x, a0.y, a0.z, a0.w, a1.x, a1.y,
                          a1.z, a1.w, a2.x, a2.y, a2.z, a2.w};
    const float wy[12] = {b0.x, b0.y, b0.z, b0.w, b1.x, b1.y,
                          b1.z, b1.w, b2.x, b2.y, b2.z, b2.w};

    float h0[4], h1[4], h2[4], h3[4], h4[4];
#pragma unroll
    for (int p = 0; p < 4; ++p) {
      h0[p] = 0.f; h1[p] = 0.f; h2[p] = 0.f; h3[p] = 0.f; h4[p] = 0.f;
    }
#pragma unroll
    for (int k = 0; k < 7; ++k) {
      const float gk = gw[k];
#pragma unroll
      for (int p = 0; p < 4; ++p) {
        const float xv = wx[1 + p + k];   // window idx 1..10
        const float yv = wy[1 + p + k];
        const float t1 = gk * xv;
        const float t2 = gk * yv;
        h0[p] += t1;
        h1[p] += t2;
        h2[p] = __builtin_fmaf(t1, xv, h2[p]);
        h3[p] = __builtin_fmaf(t2, yv, h3[p]);
        h4[p] = __builtin_fmaf(t1, yv, h4[p]);
      }
    }
    float* hb = &ho[r * 64 + 4 * g];
    *(float4*)(hb + 0 * HR * 64) = make_float4(h0[0], h0[1], h0[2], h0[3]);
    *(float4*)(hb + 1 * HR * 64) = make_float4(h1[0], h1[1], h1[2], h1[3]);
    *(float4*)(hb + 2 * HR * 64) = make_float4(h2[0], h2[1], h2[2], h2[3]);
    *(float4*)(hb + 3 * HR * 64) = make_float4(h3[0], h3[1], h3[2], h3[3]);
    *(float4*)(hb + 4 * HR * 64) = make_float4(h4[0], h4[1], h4[2], h4[3]);
  }
  __syncthreads();

  // ---- Phase V: 4 consecutive rows x 1 col per thread (tap sharing) ----
  const int c = tid & 63;                 // col 0..63 (consecutive lanes)
  const int q = tid >> 6;                 // row quad 0..3 -> out rows 4q..4q+3
  const float* vb = &ho[(4 * q) * 64 + c];

  float t0[10], t1[10], t2[10], t3[10], t4[10];
#pragma unroll
  for (int j = 0; j < 10; ++j) {
    t0[j] = vb[(0 * HR + j) * 64];
    t1[j] = vb[(1 * HR + j) * 64];
    t2[j] = vb[(2 * HR + j) * 64];
    t3[j] = vb[(3 * HR + j) * 64];
    t4[j] = vb[(4 * HR + j) * 64];
  }

  float ssim_acc = 0.f;
#pragma unroll
  for (int m = 0; m < 4; ++m) {
    float mu1 = 0.f, mu2 = 0.f, exx = 0.f, eyy = 0.f, exy = 0.f;
#pragma unroll
    for (int k = 0; k < 7; ++k) {
      const float gk = gw[k];
      mu1 = __builtin_fmaf(gk, t0[m + k], mu1);
      mu2 = __builtin_fmaf(gk, t1[m + k], mu2);
      exx = __builtin_fmaf(gk, t2[m + k], exx);
      eyy = __builtin_fmaf(gk, t3[m + k], eyy);
      exy = __builtin_fmaf(gk, t4[m + k], exy);
    }
    const float mu1sq = mu1 * mu1;
    const float mu2sq = mu2 * mu2;
    const float mu12 = mu1 * mu2;
    const float sig1 = exx - mu1sq;
    const float sig2 = eyy - mu2sq;
    const float sig12 = exy - mu12;
    const float num = (2.f * mu12 + SSIM_C1) * (2.f * sig12 + SSIM_C2);
    const float den = (mu1sq + mu2sq + SSIM_C1) * (sig1 + sig2 + SSIM_C2);
    ssim_acc += num * __builtin_amdgcn_rcpf(den);
  }

  // ---- Reduce (4 waves) + atomic fold-in ----
#pragma unroll
  for (int off = 32; off > 0; off >>= 1)
    ssim_acc += __shfl_down(ssim_acc, off, 64);
  __shared__ float wsum[4];
  if ((tid & 63) == 0) wsum[tid >> 6] = ssim_acc;
  __syncthreads();
  if (tid == 0) {
    const float s = wsum[0] + wsum[1] + wsum[2] + wsum[3];
    const float inv_n = 1.0f / (48.0f * 512.0f * 512.0f);
    atomicAdd(out, 1.0f / (float)NBLK - s * inv_n);
  }
}

extern "C" void kernel_launch(void* const* d_in, const int* in_sizes, int n_in,
                              void* d_out, int out_size, void* d_ws, size_t ws_size,
                              hipStream_t stream) {
  const float* enhanced = (const float*)d_in[0];
  const float* target = (const float*)d_in[1];
  float* out = (float*)d_out;

  hipMemsetAsync(out, 0, sizeof(float), stream);
  dim3 grid(IMG / TW, IMG / TH, 48);   // 8 x 32 x 48 = 12288
  ssim_main<<<grid, dim3(256), 0, stream>>>(enhanced, target, out);
}